// Round 1
// baseline (6535.164 us; speedup 1.0000x reference)
//
#include <hip/hip_runtime.h>

#define N_NODES 50000
#define N_EDGES 1600000
#define R_REL 8
#define G_GRAPHS 64
#define D_INF 128
#define HIDF 128
#define CLSF 10

// K dimension of the fused per-layer GEMM: R*D (relation part) + D (root part)
#define KTOT 1152
#define KREL 1024

// ---------------- count edges per (dst, rel) segment ----------------
__global__ void count_kernel(const int* __restrict__ dst, const int* __restrict__ et,
                             float* __restrict__ cnt) {
    int e = blockIdx.x * blockDim.x + threadIdx.x;
    if (e < N_EDGES) {
        atomicAdd(&cnt[dst[e] * R_REL + et[e]], 1.0f);
    }
}

__global__ void invert_kernel(float* __restrict__ cnt) {
    int i = blockIdx.x * blockDim.x + threadIdx.x;
    if (i < N_NODES * R_REL) {
        cnt[i] = 1.0f / fmaxf(cnt[i], 1.0f);
    }
}

// ---------------- scatter-add features into (dst, rel) segments ----------------
// One 32-lane group per edge; each lane handles 4 consecutive floats (float4 read,
// 4 fp32 global atomics).
__global__ void scatter_kernel(const float* __restrict__ feat,
                               const int* __restrict__ src,
                               const int* __restrict__ dst,
                               const int* __restrict__ et,
                               float* __restrict__ agg) {
    int tid = blockIdx.x * blockDim.x + threadIdx.x;
    int e = tid >> 5;
    int c = tid & 31;
    if (e < N_EDGES) {
        int s = src[e];
        int seg = dst[e] * R_REL + et[e];
        float4 v = ((const float4*)(feat + (size_t)s * D_INF))[c];
        float* base = agg + (size_t)seg * D_INF + c * 4;
        atomicAdd(base + 0, v.x);
        atomicAdd(base + 1, v.y);
        atomicAdd(base + 2, v.z);
        atomicAdd(base + 3, v.w);
    }
}

// ---------------- fused RGCN layer GEMM ----------------
// out[n][h] = relu( sum_{k<1024} agg[n][k]*invc[n][k>>7] * Wf[k][h]
//                 + sum_{k<128}  xin[n][k] * root[k][h] + bias[h] )
#define BM 64
#define BN 128
#define BK 16

__global__ __launch_bounds__(256) void gemm_kernel(
    const float* __restrict__ agg,   // [N, 1024]
    const float* __restrict__ invc,  // [N, 8]
    const float* __restrict__ xin,   // [N, 128]
    const float* __restrict__ Wf,    // [1024, 128]
    const float* __restrict__ root,  // [128, 128]
    const float* __restrict__ bias,  // [128]
    float* __restrict__ out)         // [N, 128]
{
    __shared__ float As[BK][BM + 4];
    __shared__ float Bs[BK][BN + 4];

    const int tx = threadIdx.x;
    const int row0 = blockIdx.x * BM;

    const int cg = tx & 31;      // column group 0..31
    const int rg = tx >> 5;      // row group 0..7
    const int n0 = cg * 4;
    const int m0 = rg * 8;

    const int a_m = tx >> 2;          // 0..63
    const int a_k = (tx & 3) * 4;     // 0,4,8,12
    const int a_row = row0 + a_m;
    const bool a_valid = a_row < N_NODES;

    float acc[8][4];
#pragma unroll
    for (int i = 0; i < 8; i++)
#pragma unroll
        for (int j = 0; j < 4; j++) acc[i][j] = 0.0f;

    for (int k0 = 0; k0 < KTOT; k0 += BK) {
        // ---- load A tile (64 x 16), fused mean-division ----
        {
            int k = k0 + a_k;
            float4 v = make_float4(0.f, 0.f, 0.f, 0.f);
            if (a_valid) {
                if (k < KREL) {
                    v = *(const float4*)(agg + (size_t)a_row * KREL + k);
                    float s = invc[a_row * R_REL + (k >> 7)];
                    v.x *= s; v.y *= s; v.z *= s; v.w *= s;
                } else {
                    v = *(const float4*)(xin + (size_t)a_row * D_INF + (k - KREL));
                }
            }
            As[a_k + 0][a_m] = v.x;
            As[a_k + 1][a_m] = v.y;
            As[a_k + 2][a_m] = v.z;
            As[a_k + 3][a_m] = v.w;
        }
        // ---- load B tile (16 x 128) ----
#pragma unroll
        for (int l = 0; l < 2; l++) {
            int idx = tx + l * 256;
            int bk = idx >> 5;            // 0..15
            int bc = (idx & 31) * 4;      // 0..124
            int k = k0 + bk;
            float4 v;
            if (k < KREL) v = *(const float4*)(Wf + (size_t)k * HIDF + bc);
            else          v = *(const float4*)(root + (size_t)(k - KREL) * HIDF + bc);
            *(float4*)&Bs[bk][bc] = v;
        }
        __syncthreads();

#pragma unroll
        for (int k = 0; k < BK; k++) {
            float a[8];
#pragma unroll
            for (int i = 0; i < 8; i++) a[i] = As[k][m0 + i];
            float4 b = *(const float4*)&Bs[k][n0];
#pragma unroll
            for (int i = 0; i < 8; i++) {
                acc[i][0] += a[i] * b.x;
                acc[i][1] += a[i] * b.y;
                acc[i][2] += a[i] * b.z;
                acc[i][3] += a[i] * b.w;
            }
        }
        __syncthreads();
    }

#pragma unroll
    for (int i = 0; i < 8; i++) {
        int row = row0 + m0 + i;
        if (row < N_NODES) {
            float4 o;
            o.x = fmaxf(acc[i][0] + bias[n0 + 0], 0.0f);
            o.y = fmaxf(acc[i][1] + bias[n0 + 1], 0.0f);
            o.z = fmaxf(acc[i][2] + bias[n0 + 2], 0.0f);
            o.w = fmaxf(acc[i][3] + bias[n0 + 3], 0.0f);
            *(float4*)(out + (size_t)row * HIDF + n0) = o;
        }
    }
}

// ---------------- global mean pool ----------------
__global__ void pool_kernel(const float* __restrict__ h,
                            const int* __restrict__ batch,
                            float* __restrict__ gsum,
                            float* __restrict__ gcnt) {
    int tid = blockIdx.x * blockDim.x + threadIdx.x;
    int n = tid >> 5;
    int c = tid & 31;
    if (n < N_NODES) {
        int g = batch[n];
        float4 v = ((const float4*)(h + (size_t)n * HIDF))[c];
        float* base = gsum + g * HIDF + c * 4;
        atomicAdd(base + 0, v.x);
        atomicAdd(base + 1, v.y);
        atomicAdd(base + 2, v.z);
        atomicAdd(base + 3, v.w);
        if (c == 0) atomicAdd(&gcnt[g], 1.0f);
    }
}

// ---------------- final linear ----------------
__global__ void final_kernel(const float* __restrict__ gsum,
                             const float* __restrict__ gcnt,
                             const float* __restrict__ lin_w,  // [128, 10]
                             const float* __restrict__ lin_b,  // [10]
                             float* __restrict__ out) {        // [64, 10]
    __shared__ float gl[HIDF];
    int g = blockIdx.x;
    int hh = threadIdx.x;
    gl[hh] = gsum[g * HIDF + hh] / fmaxf(gcnt[g], 1.0f);
    __syncthreads();
    if (hh < CLSF) {
        float s = lin_b[hh];
#pragma unroll 16
        for (int d = 0; d < HIDF; d++) s += gl[d] * lin_w[d * CLSF + hh];
        out[g * CLSF + hh] = s;
    }
}

extern "C" void kernel_launch(void* const* d_in, const int* in_sizes, int n_in,
                              void* d_out, int out_size, void* d_ws, size_t ws_size,
                              hipStream_t stream) {
    const float* x     = (const float*)d_in[0];
    const int*   ei    = (const int*)d_in[1];
    const int*   et    = (const int*)d_in[2];
    const int*   batch = (const int*)d_in[3];
    const float* W1    = (const float*)d_in[4];
    const float* root1 = (const float*)d_in[5];
    const float* b1    = (const float*)d_in[6];
    const float* W2    = (const float*)d_in[7];
    const float* root2 = (const float*)d_in[8];
    const float* b2    = (const float*)d_in[9];
    const float* lin_w = (const float*)d_in[10];
    const float* lin_b = (const float*)d_in[11];
    float* out = (float*)d_out;

    const int* src = ei;            // edge_index[0]
    const int* dst = ei + N_EDGES;  // edge_index[1]

    char* ws = (char*)d_ws;
    float* agg  = (float*)ws; ws += (size_t)N_NODES * KREL * 4;    // 204.8 MB
    float* cnt  = (float*)ws; ws += (size_t)N_NODES * R_REL * 4;   // 1.6 MB
    float* h1   = (float*)ws; ws += (size_t)N_NODES * HIDF * 4;    // 25.6 MB
    float* h2   = (float*)ws; ws += (size_t)N_NODES * HIDF * 4;    // 25.6 MB
    float* gsum = (float*)ws; ws += (size_t)G_GRAPHS * HIDF * 4;   // 32 KB
    float* gcnt = (float*)ws; ws += (size_t)G_GRAPHS * 4;

    // zero accumulators (d_ws is poisoned to 0xAA before every call)
    hipMemsetAsync(cnt, 0, (size_t)N_NODES * R_REL * 4, stream);
    hipMemsetAsync(agg, 0, (size_t)N_NODES * KREL * 4, stream);
    hipMemsetAsync(gsum, 0, (size_t)(G_GRAPHS * HIDF + G_GRAPHS) * 4, stream);

    // segment counts (topology only — shared by both layers)
    count_kernel<<<(N_EDGES + 255) / 256, 256, 0, stream>>>(dst, et, cnt);
    invert_kernel<<<(N_NODES * R_REL + 255) / 256, 256, 0, stream>>>(cnt);

    // ---- layer 1 ----
    scatter_kernel<<<(N_EDGES * 32) / 256, 256, 0, stream>>>(x, src, dst, et, agg);
    gemm_kernel<<<(N_NODES + BM - 1) / BM, 256, 0, stream>>>(agg, cnt, x, W1, root1, b1, h1);

    // ---- layer 2 ----
    hipMemsetAsync(agg, 0, (size_t)N_NODES * KREL * 4, stream);
    scatter_kernel<<<(N_EDGES * 32) / 256, 256, 0, stream>>>(h1, src, dst, et, agg);
    gemm_kernel<<<(N_NODES + BM - 1) / BM, 256, 0, stream>>>(agg, cnt, h1, W2, root2, b2, h2);

    // ---- pool + classify ----
    pool_kernel<<<(N_NODES * 32 + 255) / 256, 256, 0, stream>>>(h2, batch, gsum, gcnt);
    final_kernel<<<G_GRAPHS, HIDF, 0, stream>>>(gsum, gcnt, lin_w, lin_b, out);

    (void)in_sizes; (void)n_in; (void)out_size; (void)ws_size;
}

// Round 2
// 1480.453 us; speedup vs baseline: 4.4143x; 4.4143x over previous
//
#include <hip/hip_runtime.h>

#define N_NODES 50000
#define N_EDGES 1600000
#define R_REL 8
#define G_GRAPHS 64
#define D_INF 128
#define HIDF 128
#define CLSF 10

#define S_SEG (N_NODES * R_REL)   // 400000 (dst, rel) segments

// K dimension of the fused per-layer GEMM: R*D (relation part) + D (root part)
#define KTOT 1152
#define KREL 1024

// ---------------- count edges per (dst, rel) segment ----------------
__global__ void count_kernel(const int* __restrict__ dst, const int* __restrict__ et,
                             int* __restrict__ cnt) {
    int e = blockIdx.x * blockDim.x + threadIdx.x;
    if (e < N_EDGES) {
        atomicAdd(&cnt[dst[e] * R_REL + et[e]], 1);
    }
}

// ---------------- two-level exclusive scan over segment counts ----------------
#define SCAN_BLK 256
#define SCAN_ELEMS 1024
#define NB_SCAN ((S_SEG + SCAN_ELEMS - 1) / SCAN_ELEMS)   // 391

// per-block exclusive scan (1024 elems / 256 threads), block totals to bsum
__global__ __launch_bounds__(SCAN_BLK) void scan1_kernel(const int* __restrict__ cnt,
                                                         int* __restrict__ off,
                                                         int* __restrict__ bsum) {
    __shared__ int sd[SCAN_BLK];
    int t = threadIdx.x;
    int base = blockIdx.x * SCAN_ELEMS + t * 4;
    int v[4];
    int tsum = 0;
#pragma unroll
    for (int j = 0; j < 4; j++) {
        v[j] = (base + j < S_SEG) ? cnt[base + j] : 0;
        tsum += v[j];
    }
    sd[t] = tsum;
    __syncthreads();
    // Hillis-Steele inclusive scan over thread sums
    for (int d = 1; d < SCAN_BLK; d <<= 1) {
        int x = (t >= d) ? sd[t - d] : 0;
        __syncthreads();
        sd[t] += x;
        __syncthreads();
    }
    int incl = sd[t];
    int run = incl - tsum;   // exclusive base for this thread
#pragma unroll
    for (int j = 0; j < 4; j++) {
        if (base + j < S_SEG) off[base + j] = run;
        run += v[j];
    }
    if (t == SCAN_BLK - 1) bsum[blockIdx.x] = incl;
}

// single-block exclusive scan of the 391 block totals
__global__ __launch_bounds__(512) void scan2_kernel(int* __restrict__ bsum) {
    __shared__ int sd[512];
    int t = threadIdx.x;
    int v = (t < NB_SCAN) ? bsum[t] : 0;
    sd[t] = v;
    __syncthreads();
    for (int d = 1; d < 512; d <<= 1) {
        int x = (t >= d) ? sd[t - d] : 0;
        __syncthreads();
        sd[t] += x;
        __syncthreads();
    }
    if (t < NB_SCAN) bsum[t] = sd[t] - v;   // exclusive
}

// ---------------- bin edges into segment-sorted src list ----------------
__global__ void bin_kernel(const int* __restrict__ src,
                           const int* __restrict__ dst,
                           const int* __restrict__ et,
                           const int* __restrict__ off,
                           const int* __restrict__ bsum,
                           int* __restrict__ cursor,
                           int* __restrict__ sorted_src) {
    int e = blockIdx.x * blockDim.x + threadIdx.x;
    if (e < N_EDGES) {
        int seg = dst[e] * R_REL + et[e];
        int pos = atomicAdd(&cursor[seg], 1);
        sorted_src[off[seg] + bsum[seg >> 10] + pos] = src[e];
    }
}

// ---------------- gather-aggregate: per-segment mean, no atomics ----------------
// One 32-lane group per segment; lane c covers floats [4c, 4c+4).
__global__ __launch_bounds__(256) void agg_kernel(const float* __restrict__ feat,
                                                  const int* __restrict__ sorted_src,
                                                  const int* __restrict__ off,
                                                  const int* __restrict__ bsum,
                                                  const int* __restrict__ cnt,
                                                  float* __restrict__ mean) {
    int g = blockIdx.x * 8 + (threadIdx.x >> 5);
    if (g >= S_SEG) return;
    int c = threadIdx.x & 31;
    int n = cnt[g];
    int beg = off[g] + bsum[g >> 10];
    float4 s = make_float4(0.f, 0.f, 0.f, 0.f);
    for (int i = 0; i < n; i++) {
        int sn = sorted_src[beg + i];
        float4 v = ((const float4*)(feat + (size_t)sn * D_INF))[c];
        s.x += v.x; s.y += v.y; s.z += v.z; s.w += v.w;
    }
    float inv = 1.0f / (float)max(n, 1);
    s.x *= inv; s.y *= inv; s.z *= inv; s.w *= inv;
    ((float4*)(mean + (size_t)g * D_INF))[c] = s;
}

// ---------------- fused RGCN layer GEMM ----------------
// out[n][h] = relu( mean_flat[n, 0:1024] @ Wf + xin[n,0:128] @ root + bias )
#define BM 64
#define BN 128
#define BK 16

__global__ __launch_bounds__(256) void gemm_kernel(
    const float* __restrict__ mean,  // [N, 1024] (already mean-divided)
    const float* __restrict__ xin,   // [N, 128]
    const float* __restrict__ Wf,    // [1024, 128]
    const float* __restrict__ root,  // [128, 128]
    const float* __restrict__ bias,  // [128]
    float* __restrict__ out)         // [N, 128]
{
    __shared__ float As[BK][BM + 4];
    __shared__ float Bs[BK][BN + 4];

    const int tx = threadIdx.x;
    const int row0 = blockIdx.x * BM;

    const int cg = tx & 31;      // column group 0..31
    const int rg = tx >> 5;      // row group 0..7
    const int n0 = cg * 4;
    const int m0 = rg * 8;

    const int a_m = tx >> 2;          // 0..63
    const int a_k = (tx & 3) * 4;     // 0,4,8,12
    const int a_row = row0 + a_m;
    const bool a_valid = a_row < N_NODES;

    float acc[8][4];
#pragma unroll
    for (int i = 0; i < 8; i++)
#pragma unroll
        for (int j = 0; j < 4; j++) acc[i][j] = 0.0f;

    for (int k0 = 0; k0 < KTOT; k0 += BK) {
        // ---- load A tile (64 x 16) ----
        {
            int k = k0 + a_k;
            float4 v = make_float4(0.f, 0.f, 0.f, 0.f);
            if (a_valid) {
                if (k < KREL) v = *(const float4*)(mean + (size_t)a_row * KREL + k);
                else          v = *(const float4*)(xin + (size_t)a_row * D_INF + (k - KREL));
            }
            As[a_k + 0][a_m] = v.x;
            As[a_k + 1][a_m] = v.y;
            As[a_k + 2][a_m] = v.z;
            As[a_k + 3][a_m] = v.w;
        }
        // ---- load B tile (16 x 128) ----
#pragma unroll
        for (int l = 0; l < 2; l++) {
            int idx = tx + l * 256;
            int bk = idx >> 5;            // 0..15
            int bc = (idx & 31) * 4;      // 0..124
            int k = k0 + bk;
            float4 v;
            if (k < KREL) v = *(const float4*)(Wf + (size_t)k * HIDF + bc);
            else          v = *(const float4*)(root + (size_t)(k - KREL) * HIDF + bc);
            *(float4*)&Bs[bk][bc] = v;
        }
        __syncthreads();

#pragma unroll
        for (int k = 0; k < BK; k++) {
            float a[8];
#pragma unroll
            for (int i = 0; i < 8; i++) a[i] = As[k][m0 + i];
            float4 b = *(const float4*)&Bs[k][n0];
#pragma unroll
            for (int i = 0; i < 8; i++) {
                acc[i][0] += a[i] * b.x;
                acc[i][1] += a[i] * b.y;
                acc[i][2] += a[i] * b.z;
                acc[i][3] += a[i] * b.w;
            }
        }
        __syncthreads();
    }

#pragma unroll
    for (int i = 0; i < 8; i++) {
        int row = row0 + m0 + i;
        if (row < N_NODES) {
            float4 o;
            o.x = fmaxf(acc[i][0] + bias[n0 + 0], 0.0f);
            o.y = fmaxf(acc[i][1] + bias[n0 + 1], 0.0f);
            o.z = fmaxf(acc[i][2] + bias[n0 + 2], 0.0f);
            o.w = fmaxf(acc[i][3] + bias[n0 + 3], 0.0f);
            *(float4*)(out + (size_t)row * HIDF + n0) = o;
        }
    }
}

// ---------------- global mean pool ----------------
__global__ void pool_kernel(const float* __restrict__ h,
                            const int* __restrict__ batch,
                            float* __restrict__ gsum,
                            float* __restrict__ gcnt) {
    int tid = blockIdx.x * blockDim.x + threadIdx.x;
    int n = tid >> 5;
    int c = tid & 31;
    if (n < N_NODES) {
        int g = batch[n];
        float4 v = ((const float4*)(h + (size_t)n * HIDF))[c];
        float* base = gsum + g * HIDF + c * 4;
        atomicAdd(base + 0, v.x);
        atomicAdd(base + 1, v.y);
        atomicAdd(base + 2, v.z);
        atomicAdd(base + 3, v.w);
        if (c == 0) atomicAdd(&gcnt[g], 1.0f);
    }
}

// ---------------- final linear ----------------
__global__ void final_kernel(const float* __restrict__ gsum,
                             const float* __restrict__ gcnt,
                             const float* __restrict__ lin_w,  // [128, 10]
                             const float* __restrict__ lin_b,  // [10]
                             float* __restrict__ out) {        // [64, 10]
    __shared__ float gl[HIDF];
    int g = blockIdx.x;
    int hh = threadIdx.x;
    gl[hh] = gsum[g * HIDF + hh] / fmaxf(gcnt[g], 1.0f);
    __syncthreads();
    if (hh < CLSF) {
        float s = lin_b[hh];
#pragma unroll 16
        for (int d = 0; d < HIDF; d++) s += gl[d] * lin_w[d * CLSF + hh];
        out[g * CLSF + hh] = s;
    }
}

extern "C" void kernel_launch(void* const* d_in, const int* in_sizes, int n_in,
                              void* d_out, int out_size, void* d_ws, size_t ws_size,
                              hipStream_t stream) {
    const float* x     = (const float*)d_in[0];
    const int*   ei    = (const int*)d_in[1];
    const int*   et    = (const int*)d_in[2];
    const int*   batch = (const int*)d_in[3];
    const float* W1    = (const float*)d_in[4];
    const float* root1 = (const float*)d_in[5];
    const float* b1    = (const float*)d_in[6];
    const float* W2    = (const float*)d_in[7];
    const float* root2 = (const float*)d_in[8];
    const float* b2    = (const float*)d_in[9];
    const float* lin_w = (const float*)d_in[10];
    const float* lin_b = (const float*)d_in[11];
    float* out = (float*)d_out;

    const int* src = ei;            // edge_index[0]
    const int* dst = ei + N_EDGES;  // edge_index[1]

    char* ws = (char*)d_ws;
    float* mean   = (float*)ws; ws += (size_t)S_SEG * D_INF * 4;     // 204.8 MB
    int*   cnt    = (int*)ws;   ws += (size_t)S_SEG * 4;             // 1.6 MB
    int*   off    = (int*)ws;   ws += (size_t)S_SEG * 4;             // 1.6 MB
    int*   bsum   = (int*)ws;   ws += 512 * 4;                       // block totals
    int*   cursor = (int*)ws;   ws += (size_t)S_SEG * 4;             // 1.6 MB
    int*   sorted_src = (int*)ws; ws += (size_t)N_EDGES * 4;         // 6.4 MB
    float* h1     = (float*)ws; ws += (size_t)N_NODES * HIDF * 4;    // 25.6 MB
    float* gsum   = (float*)ws; ws += (size_t)G_GRAPHS * HIDF * 4;
    float* gcnt   = (float*)ws; ws += (size_t)G_GRAPHS * 4;

    // zero what must be zero (ws is poisoned to 0xAA before every call)
    hipMemsetAsync(cnt, 0, (size_t)S_SEG * 4, stream);
    hipMemsetAsync(cursor, 0, (size_t)S_SEG * 4, stream);
    hipMemsetAsync(gsum, 0, (size_t)(G_GRAPHS * HIDF + G_GRAPHS) * 4, stream);

    // ---- counting sort of edges by (dst, rel) segment ----
    count_kernel<<<(N_EDGES + 255) / 256, 256, 0, stream>>>(dst, et, cnt);
    scan1_kernel<<<NB_SCAN, SCAN_BLK, 0, stream>>>(cnt, off, bsum);
    scan2_kernel<<<1, 512, 0, stream>>>(bsum);
    bin_kernel<<<(N_EDGES + 255) / 256, 256, 0, stream>>>(src, dst, et, off, bsum,
                                                          cursor, sorted_src);

    // ---- layer 1 ----
    agg_kernel<<<(S_SEG + 7) / 8, 256, 0, stream>>>(x, sorted_src, off, bsum, cnt, mean);
    gemm_kernel<<<(N_NODES + BM - 1) / BM, 256, 0, stream>>>(mean, x, W1, root1, b1, h1);

    // ---- layer 2 (GEMM in-place: each block reads only its own row tile) ----
    agg_kernel<<<(S_SEG + 7) / 8, 256, 0, stream>>>(h1, sorted_src, off, bsum, cnt, mean);
    gemm_kernel<<<(N_NODES + BM - 1) / BM, 256, 0, stream>>>(mean, h1, W2, root2, b2, h1);

    // ---- pool + classify ----
    pool_kernel<<<(N_NODES * 32 + 255) / 256, 256, 0, stream>>>(h1, batch, gsum, gcnt);
    final_kernel<<<G_GRAPHS, HIDF, 0, stream>>>(gsum, gcnt, lin_w, lin_b, out);

    (void)in_sizes; (void)n_in; (void)out_size; (void)ws_size;
}

// Round 3
// 1156.827 us; speedup vs baseline: 5.6492x; 1.2798x over previous
//
#include <hip/hip_runtime.h>

#define N_NODES 50000
#define N_EDGES 1600000
#define R_REL 8
#define G_GRAPHS 64
#define D_INF 128
#define HIDF 128
#define CLSF 10

#define S_SEG (N_NODES * R_REL)   // 400000 (dst, rel) segments

// K dimension of the fused per-layer GEMM: R*D (relation part) + D (root part)
#define KTOT 1152
#define KREL 1024

// ---------------- count edges per (dst, rel) segment ----------------
__global__ void count_kernel(const int* __restrict__ dst, const int* __restrict__ et,
                             int* __restrict__ cnt) {
    int e = blockIdx.x * blockDim.x + threadIdx.x;
    if (e < N_EDGES) {
        atomicAdd(&cnt[dst[e] * R_REL + et[e]], 1);
    }
}

// ---------------- two-level exclusive scan over segment counts ----------------
#define SCAN_BLK 256
#define SCAN_ELEMS 1024
#define NB_SCAN ((S_SEG + SCAN_ELEMS - 1) / SCAN_ELEMS)   // 391

__global__ __launch_bounds__(SCAN_BLK) void scan1_kernel(const int* __restrict__ cnt,
                                                         int* __restrict__ off,
                                                         int* __restrict__ bsum) {
    __shared__ int sd[SCAN_BLK];
    int t = threadIdx.x;
    int base = blockIdx.x * SCAN_ELEMS + t * 4;
    int v[4];
    int tsum = 0;
#pragma unroll
    for (int j = 0; j < 4; j++) {
        v[j] = (base + j < S_SEG) ? cnt[base + j] : 0;
        tsum += v[j];
    }
    sd[t] = tsum;
    __syncthreads();
    for (int d = 1; d < SCAN_BLK; d <<= 1) {
        int x = (t >= d) ? sd[t - d] : 0;
        __syncthreads();
        sd[t] += x;
        __syncthreads();
    }
    int incl = sd[t];
    int run = incl - tsum;
#pragma unroll
    for (int j = 0; j < 4; j++) {
        if (base + j < S_SEG) off[base + j] = run;
        run += v[j];
    }
    if (t == SCAN_BLK - 1) bsum[blockIdx.x] = incl;
}

__global__ __launch_bounds__(512) void scan2_kernel(int* __restrict__ bsum) {
    __shared__ int sd[512];
    int t = threadIdx.x;
    int v = (t < NB_SCAN) ? bsum[t] : 0;
    sd[t] = v;
    __syncthreads();
    for (int d = 1; d < 512; d <<= 1) {
        int x = (t >= d) ? sd[t - d] : 0;
        __syncthreads();
        sd[t] += x;
        __syncthreads();
    }
    if (t < NB_SCAN) bsum[t] = sd[t] - v;
}

// ---------------- bin edges into segment-sorted src list ----------------
__global__ void bin_kernel(const int* __restrict__ src,
                           const int* __restrict__ dst,
                           const int* __restrict__ et,
                           const int* __restrict__ off,
                           const int* __restrict__ bsum,
                           int* __restrict__ cursor,
                           int* __restrict__ sorted_src) {
    int e = blockIdx.x * blockDim.x + threadIdx.x;
    if (e < N_EDGES) {
        int seg = dst[e] * R_REL + et[e];
        int pos = atomicAdd(&cursor[seg], 1);
        sorted_src[off[seg] + bsum[seg >> 10] + pos] = src[e];
    }
}

// ---------------- gather-aggregate: per-segment mean, no atomics ----------------
__global__ __launch_bounds__(256) void agg_kernel(const float* __restrict__ feat,
                                                  const int* __restrict__ sorted_src,
                                                  const int* __restrict__ off,
                                                  const int* __restrict__ bsum,
                                                  const int* __restrict__ cnt,
                                                  float* __restrict__ mean) {
    int g = blockIdx.x * 8 + (threadIdx.x >> 5);
    if (g >= S_SEG) return;
    int c = threadIdx.x & 31;
    int n = cnt[g];
    int beg = off[g] + bsum[g >> 10];
    float4 s = make_float4(0.f, 0.f, 0.f, 0.f);
    for (int i = 0; i < n; i++) {
        int sn = sorted_src[beg + i];
        float4 v = ((const float4*)(feat + (size_t)sn * D_INF))[c];
        s.x += v.x; s.y += v.y; s.z += v.z; s.w += v.w;
    }
    float inv = 1.0f / (float)max(n, 1);
    s.x *= inv; s.y *= inv; s.z *= inv; s.w *= inv;
    ((float4*)(mean + (size_t)g * D_INF))[c] = s;
}

// ---------------- fused RGCN layer GEMM ----------------
#define BM 64
#define BN 128
#define BK 16

__global__ __launch_bounds__(256) void gemm_kernel(
    const float* __restrict__ mean,  // [N, 1024] (already mean-divided)
    const float* __restrict__ xin,   // [N, 128]
    const float* __restrict__ Wf,    // [1024, 128]
    const float* __restrict__ root,  // [128, 128]
    const float* __restrict__ bias,  // [128]
    float* __restrict__ out)         // [N, 128]
{
    __shared__ float As[BK][BM + 4];
    __shared__ float Bs[BK][BN + 4];

    const int tx = threadIdx.x;
    const int row0 = blockIdx.x * BM;

    const int cg = tx & 31;
    const int rg = tx >> 5;
    const int n0 = cg * 4;
    const int m0 = rg * 8;

    const int a_m = tx >> 2;
    const int a_k = (tx & 3) * 4;
    const int a_row = row0 + a_m;
    const bool a_valid = a_row < N_NODES;

    float acc[8][4];
#pragma unroll
    for (int i = 0; i < 8; i++)
#pragma unroll
        for (int j = 0; j < 4; j++) acc[i][j] = 0.0f;

    for (int k0 = 0; k0 < KTOT; k0 += BK) {
        {
            int k = k0 + a_k;
            float4 v = make_float4(0.f, 0.f, 0.f, 0.f);
            if (a_valid) {
                if (k < KREL) v = *(const float4*)(mean + (size_t)a_row * KREL + k);
                else          v = *(const float4*)(xin + (size_t)a_row * D_INF + (k - KREL));
            }
            As[a_k + 0][a_m] = v.x;
            As[a_k + 1][a_m] = v.y;
            As[a_k + 2][a_m] = v.z;
            As[a_k + 3][a_m] = v.w;
        }
#pragma unroll
        for (int l = 0; l < 2; l++) {
            int idx = tx + l * 256;
            int bk = idx >> 5;
            int bc = (idx & 31) * 4;
            int k = k0 + bk;
            float4 v;
            if (k < KREL) v = *(const float4*)(Wf + (size_t)k * HIDF + bc);
            else          v = *(const float4*)(root + (size_t)(k - KREL) * HIDF + bc);
            *(float4*)&Bs[bk][bc] = v;
        }
        __syncthreads();

#pragma unroll
        for (int k = 0; k < BK; k++) {
            float a[8];
#pragma unroll
            for (int i = 0; i < 8; i++) a[i] = As[k][m0 + i];
            float4 b = *(const float4*)&Bs[k][n0];
#pragma unroll
            for (int i = 0; i < 8; i++) {
                acc[i][0] += a[i] * b.x;
                acc[i][1] += a[i] * b.y;
                acc[i][2] += a[i] * b.z;
                acc[i][3] += a[i] * b.w;
            }
        }
        __syncthreads();
    }

#pragma unroll
    for (int i = 0; i < 8; i++) {
        int row = row0 + m0 + i;
        if (row < N_NODES) {
            float4 o;
            o.x = fmaxf(acc[i][0] + bias[n0 + 0], 0.0f);
            o.y = fmaxf(acc[i][1] + bias[n0 + 1], 0.0f);
            o.z = fmaxf(acc[i][2] + bias[n0 + 2], 0.0f);
            o.w = fmaxf(acc[i][3] + bias[n0 + 3], 0.0f);
            *(float4*)(out + (size_t)row * HIDF + n0) = o;
        }
    }
}

// ---------------- global mean pool (batch is SORTED -> per-graph ranges) ----------------
// One block per graph: binary-search [lo,hi) node range, coalesced column sums.
__global__ __launch_bounds__(256) void pool_kernel(const float* __restrict__ h,
                                                   const int* __restrict__ batch,
                                                   float* __restrict__ gmean) {
    int g = blockIdx.x;
    // lower_bound(batch, g) and lower_bound(batch, g+1) — wave-uniform search
    int lo = 0, hi = N_NODES;
    {
        int l = 0, r = N_NODES;
        while (l < r) { int m = (l + r) >> 1; if (batch[m] < g) l = m + 1; else r = m; }
        lo = l;
        l = lo; r = N_NODES;
        while (l < r) { int m = (l + r) >> 1; if (batch[m] < g + 1) l = m + 1; else r = m; }
        hi = l;
    }
    int t = threadIdx.x;
    int c = t & 127;      // channel
    int half = t >> 7;    // 0/1: even/odd rows
    float s = 0.0f;
    for (int n = lo + half; n < hi; n += 2) {
        s += h[(size_t)n * HIDF + c];
    }
    __shared__ float red[256];
    red[t] = s;
    __syncthreads();
    if (t < 128) {
        float tot = red[t] + red[t + 128];
        int n = hi - lo;
        gmean[g * HIDF + t] = tot / (float)max(n, 1);
    }
}

// ---------------- final linear ----------------
__global__ void final_kernel(const float* __restrict__ gmean,
                             const float* __restrict__ lin_w,  // [128, 10]
                             const float* __restrict__ lin_b,  // [10]
                             float* __restrict__ out) {        // [64, 10]
    __shared__ float gl[HIDF];
    int g = blockIdx.x;
    int hh = threadIdx.x;
    gl[hh] = gmean[g * HIDF + hh];
    __syncthreads();
    if (hh < CLSF) {
        float s = lin_b[hh];
#pragma unroll 16
        for (int d = 0; d < HIDF; d++) s += gl[d] * lin_w[d * CLSF + hh];
        out[g * CLSF + hh] = s;
    }
}

extern "C" void kernel_launch(void* const* d_in, const int* in_sizes, int n_in,
                              void* d_out, int out_size, void* d_ws, size_t ws_size,
                              hipStream_t stream) {
    const float* x     = (const float*)d_in[0];
    const int*   ei    = (const int*)d_in[1];
    const int*   et    = (const int*)d_in[2];
    const int*   batch = (const int*)d_in[3];
    const float* W1    = (const float*)d_in[4];
    const float* root1 = (const float*)d_in[5];
    const float* b1    = (const float*)d_in[6];
    const float* W2    = (const float*)d_in[7];
    const float* root2 = (const float*)d_in[8];
    const float* b2    = (const float*)d_in[9];
    const float* lin_w = (const float*)d_in[10];
    const float* lin_b = (const float*)d_in[11];
    float* out = (float*)d_out;

    const int* src = ei;            // edge_index[0]
    const int* dst = ei + N_EDGES;  // edge_index[1]

    char* ws = (char*)d_ws;
    float* mean   = (float*)ws; ws += (size_t)S_SEG * D_INF * 4;     // 204.8 MB
    int*   cnt    = (int*)ws;   ws += (size_t)S_SEG * 4;             // 1.6 MB
    int*   off    = (int*)ws;   ws += (size_t)S_SEG * 4;             // 1.6 MB
    int*   bsum   = (int*)ws;   ws += 512 * 4;
    int*   cursor = (int*)ws;   ws += (size_t)S_SEG * 4;             // 1.6 MB
    int*   sorted_src = (int*)ws; ws += (size_t)N_EDGES * 4;         // 6.4 MB
    float* h1     = (float*)ws; ws += (size_t)N_NODES * HIDF * 4;    // 25.6 MB
    float* gmean  = (float*)ws; ws += (size_t)G_GRAPHS * HIDF * 4;

    hipMemsetAsync(cnt, 0, (size_t)S_SEG * 4, stream);
    hipMemsetAsync(cursor, 0, (size_t)S_SEG * 4, stream);

    // ---- counting sort of edges by (dst, rel) segment ----
    count_kernel<<<(N_EDGES + 255) / 256, 256, 0, stream>>>(dst, et, cnt);
    scan1_kernel<<<NB_SCAN, SCAN_BLK, 0, stream>>>(cnt, off, bsum);
    scan2_kernel<<<1, 512, 0, stream>>>(bsum);
    bin_kernel<<<(N_EDGES + 255) / 256, 256, 0, stream>>>(src, dst, et, off, bsum,
                                                          cursor, sorted_src);

    // ---- layer 1 ----
    agg_kernel<<<(S_SEG + 7) / 8, 256, 0, stream>>>(x, sorted_src, off, bsum, cnt, mean);
    gemm_kernel<<<(N_NODES + BM - 1) / BM, 256, 0, stream>>>(mean, x, W1, root1, b1, h1);

    // ---- layer 2 (GEMM in-place: each block reads only its own row tile) ----
    agg_kernel<<<(S_SEG + 7) / 8, 256, 0, stream>>>(h1, sorted_src, off, bsum, cnt, mean);
    gemm_kernel<<<(N_NODES + BM - 1) / BM, 256, 0, stream>>>(mean, h1, W2, root2, b2, h1);

    // ---- pool + classify (no atomics: batch is sorted) ----
    pool_kernel<<<G_GRAPHS, 256, 0, stream>>>(h1, batch, gmean);
    final_kernel<<<G_GRAPHS, HIDF, 0, stream>>>(gmean, lin_w, lin_b, out);

    (void)in_sizes; (void)n_in; (void)out_size; (void)ws_size;
}

// Round 4
// 721.630 us; speedup vs baseline: 9.0561x; 1.6031x over previous
//
#include <hip/hip_runtime.h>

#define N_NODES 50000
#define N_EDGES 1600000
#define R_REL 8
#define G_GRAPHS 64
#define D_INF 128
#define HIDF 128
#define CLSF 10

#define S_SEG (N_NODES * R_REL)   // 400000 (dst, rel) segments

// K dimension of the fused per-layer GEMM: R*D (relation part) + D (root part)
#define KTOT 1152
#define KREL 1024

typedef __attribute__((ext_vector_type(8))) short short8;
typedef __attribute__((ext_vector_type(4))) float floatx4;

__device__ __forceinline__ unsigned short f2bf(float f) {
    unsigned int u = __float_as_uint(f);
    unsigned int r = (u + 0x7fffu + ((u >> 16) & 1u)) >> 16;   // RNE
    return (unsigned short)r;
}
__device__ __forceinline__ float bf2f(unsigned short h) {
    return __uint_as_float(((unsigned int)h) << 16);
}

// ---------------- count edges per (dst, rel) segment ----------------
__global__ void count_kernel(const int* __restrict__ dst, const int* __restrict__ et,
                             int* __restrict__ cnt) {
    int e = blockIdx.x * blockDim.x + threadIdx.x;
    if (e < N_EDGES) {
        atomicAdd(&cnt[dst[e] * R_REL + et[e]], 1);
    }
}

// ---------------- two-level exclusive scan over segment counts ----------------
#define SCAN_BLK 256
#define SCAN_ELEMS 1024
#define NB_SCAN ((S_SEG + SCAN_ELEMS - 1) / SCAN_ELEMS)   // 391

__global__ __launch_bounds__(SCAN_BLK) void scan1_kernel(const int* __restrict__ cnt,
                                                         int* __restrict__ off,
                                                         int* __restrict__ bsum) {
    __shared__ int sd[SCAN_BLK];
    int t = threadIdx.x;
    int base = blockIdx.x * SCAN_ELEMS + t * 4;
    int v[4];
    int tsum = 0;
#pragma unroll
    for (int j = 0; j < 4; j++) {
        v[j] = (base + j < S_SEG) ? cnt[base + j] : 0;
        tsum += v[j];
    }
    sd[t] = tsum;
    __syncthreads();
    for (int d = 1; d < SCAN_BLK; d <<= 1) {
        int x = (t >= d) ? sd[t - d] : 0;
        __syncthreads();
        sd[t] += x;
        __syncthreads();
    }
    int incl = sd[t];
    int run = incl - tsum;
#pragma unroll
    for (int j = 0; j < 4; j++) {
        if (base + j < S_SEG) off[base + j] = run;
        run += v[j];
    }
    if (t == SCAN_BLK - 1) bsum[blockIdx.x] = incl;
}

__global__ __launch_bounds__(512) void scan2_kernel(int* __restrict__ bsum) {
    __shared__ int sd[512];
    int t = threadIdx.x;
    int v = (t < NB_SCAN) ? bsum[t] : 0;
    sd[t] = v;
    __syncthreads();
    for (int d = 1; d < 512; d <<= 1) {
        int x = (t >= d) ? sd[t - d] : 0;
        __syncthreads();
        sd[t] += x;
        __syncthreads();
    }
    if (t < NB_SCAN) bsum[t] = sd[t] - v;
}

// ---------------- bin edges into segment-sorted src list ----------------
__global__ void bin_kernel(const int* __restrict__ src,
                           const int* __restrict__ dst,
                           const int* __restrict__ et,
                           const int* __restrict__ off,
                           const int* __restrict__ bsum,
                           int* __restrict__ cursor,
                           int* __restrict__ sorted_src) {
    int e = blockIdx.x * blockDim.x + threadIdx.x;
    if (e < N_EDGES) {
        int seg = dst[e] * R_REL + et[e];
        int pos = atomicAdd(&cursor[seg], 1);
        sorted_src[off[seg] + bsum[seg >> 10] + pos] = src[e];
    }
}

// ---------------- convert x (fp32) into ab tail (bf16) ----------------
__global__ void convx_kernel(const float* __restrict__ x, unsigned short* __restrict__ ab) {
    int idx = blockIdx.x * blockDim.x + threadIdx.x;
    if (idx < N_NODES * D_INF) {
        int n = idx >> 7, c = idx & 127;
        ab[(size_t)n * KTOT + KREL + c] = f2bf(x[idx]);
    }
}

// ---------------- build transposed bf16 weights wt[128][1152] ----------------
// wt[c][k] = (k<1024 ? Wf[k][c] : root[k-1024][c]). 16x16 LDS tile transpose.
__global__ __launch_bounds__(256) void convw_kernel(const float* __restrict__ Wf,
                                                    const float* __restrict__ root,
                                                    unsigned short* __restrict__ wt) {
    __shared__ float t[16][17];
    int k0 = blockIdx.x * 16, c0 = blockIdx.y * 16;
    int tx = threadIdx.x & 15, ty = threadIdx.x >> 4;
    int k = k0 + ty, c = c0 + tx;
    float v = (k < KREL) ? Wf[(size_t)k * HIDF + c] : root[(size_t)(k - KREL) * HIDF + c];
    t[ty][tx] = v;
    __syncthreads();
    wt[(size_t)(c0 + ty) * KTOT + k0 + tx] = f2bf(t[tx][ty]);
}

// ---------------- gather-aggregate (bf16): per-segment mean, no atomics -------
// Reads feat rows from ab tail (cols 1024..1151), writes mean into ab cols 0..1023.
// One 32-lane group per segment; lane c covers 4 bf16.
__global__ __launch_bounds__(256) void agg_kernel(const unsigned short* __restrict__ ab_ro,
                                                  const int* __restrict__ sorted_src,
                                                  const int* __restrict__ off,
                                                  const int* __restrict__ bsum,
                                                  const int* __restrict__ cnt,
                                                  unsigned short* __restrict__ ab_w) {
    int g = blockIdx.x * 8 + (threadIdx.x >> 5);
    if (g >= S_SEG) return;
    int c = threadIdx.x & 31;
    int n = cnt[g];
    int beg = off[g] + bsum[g >> 10];
    float s0 = 0.f, s1 = 0.f, s2 = 0.f, s3 = 0.f;
    for (int i = 0; i < n; i++) {
        int sn = sorted_src[beg + i];
        ushort4 v = *(const ushort4*)(ab_ro + (size_t)sn * KTOT + KREL + c * 4);
        s0 += bf2f(v.x); s1 += bf2f(v.y); s2 += bf2f(v.z); s3 += bf2f(v.w);
    }
    float inv = 1.0f / (float)max(n, 1);
    ushort4 o;
    o.x = f2bf(s0 * inv); o.y = f2bf(s1 * inv); o.z = f2bf(s2 * inv); o.w = f2bf(s3 * inv);
    int node = g >> 3, rel = g & 7;
    *(ushort4*)(ab_w + (size_t)node * KTOT + rel * HIDF + c * 4) = o;
}

// ---------------- MFMA bf16 fused RGCN layer GEMM ----------------
// out[row][col] = relu( sum_k ab[row][k] * wt[col][k] + bias[col] ), bf16 out.
// 128x128 tile, BK=32, 4 waves: wave handles 32 rows x 128 cols = 2x8 frags.
__global__ __launch_bounds__(256) void gemm_mfma(
    const unsigned short* __restrict__ ab,   // [N, 1152] bf16
    const unsigned short* __restrict__ wt,   // [128, 1152] bf16 (transposed weights)
    const float* __restrict__ bias,          // [128] fp32
    unsigned short* __restrict__ dst,        // bf16 out, row stride dstride
    int dstride)
{
    __shared__ __align__(16) unsigned short Alds[128][40];   // pad 32->40: 2-way only
    __shared__ __align__(16) unsigned short Blds[128][40];

    const int tx = threadIdx.x;
    const int wave = tx >> 6, lane = tx & 63;
    const int quad = lane >> 4, lq = lane & 15;
    const int row0 = blockIdx.x * 128;

    floatx4 acc[2][8];
#pragma unroll
    for (int i = 0; i < 2; i++)
#pragma unroll
        for (int j = 0; j < 8; j++) acc[i][j] = (floatx4){0.f, 0.f, 0.f, 0.f};

    for (int k0 = 0; k0 < KTOT; k0 += 32) {
        // stage A (128 rows x 32 k) and B (128 cols x 32 k): 2 passes x 256 thr x 16B
#pragma unroll
        for (int p = 0; p < 2; p++) {
            int idx = tx + p * 256;
            int r = idx >> 2, ch = idx & 3;
            int gr = row0 + r;
            uint4 va = make_uint4(0u, 0u, 0u, 0u);
            if (gr < N_NODES) va = *(const uint4*)(ab + (size_t)gr * KTOT + k0 + ch * 8);
            *(uint4*)(&Alds[r][ch * 8]) = va;
            uint4 vb = *(const uint4*)(wt + (size_t)r * KTOT + k0 + ch * 8);
            *(uint4*)(&Blds[r][ch * 8]) = vb;
        }
        __syncthreads();

        short8 af[2], bfr[8];
#pragma unroll
        for (int i = 0; i < 2; i++)
            af[i] = *(const short8*)(&Alds[wave * 32 + i * 16 + lq][quad * 8]);
#pragma unroll
        for (int j = 0; j < 8; j++)
            bfr[j] = *(const short8*)(&Blds[j * 16 + lq][quad * 8]);
#pragma unroll
        for (int i = 0; i < 2; i++)
#pragma unroll
            for (int j = 0; j < 8; j++)
                acc[i][j] = __builtin_amdgcn_mfma_f32_16x16x32_bf16(af[i], bfr[j], acc[i][j], 0, 0, 0);
        __syncthreads();
    }

    // epilogue: C/D layout col=lane&15, row=quad*4+reg
#pragma unroll
    for (int i = 0; i < 2; i++) {
#pragma unroll
        for (int j = 0; j < 8; j++) {
#pragma unroll
            for (int r = 0; r < 4; r++) {
                int row = row0 + wave * 32 + i * 16 + quad * 4 + r;
                int col = j * 16 + lq;
                if (row < N_NODES) {
                    float v = fmaxf(acc[i][j][r] + bias[col], 0.0f);
                    dst[(size_t)row * dstride + col] = f2bf(v);
                }
            }
        }
    }
}

// ---------------- global mean pool (batch sorted -> per-graph ranges) ----------
__global__ __launch_bounds__(256) void pool_kernel(const unsigned short* __restrict__ h,
                                                   const int* __restrict__ batch,
                                                   float* __restrict__ gmean) {
    int g = blockIdx.x;
    int lo, hi;
    {
        int l = 0, r = N_NODES;
        while (l < r) { int m = (l + r) >> 1; if (batch[m] < g) l = m + 1; else r = m; }
        lo = l;
        l = lo; r = N_NODES;
        while (l < r) { int m = (l + r) >> 1; if (batch[m] < g + 1) l = m + 1; else r = m; }
        hi = l;
    }
    int t = threadIdx.x;
    int c = t & 127;
    int half = t >> 7;
    float s = 0.0f;
    for (int n = lo + half; n < hi; n += 2) {
        s += bf2f(h[(size_t)n * HIDF + c]);
    }
    __shared__ float red[256];
    red[t] = s;
    __syncthreads();
    if (t < 128) {
        float tot = red[t] + red[t + 128];
        int n = hi - lo;
        gmean[g * HIDF + t] = tot / (float)max(n, 1);
    }
}

// ---------------- final linear ----------------
__global__ void final_kernel(const float* __restrict__ gmean,
                             const float* __restrict__ lin_w,  // [128, 10]
                             const float* __restrict__ lin_b,  // [10]
                             float* __restrict__ out) {        // [64, 10]
    __shared__ float gl[HIDF];
    int g = blockIdx.x;
    int hh = threadIdx.x;
    gl[hh] = gmean[g * HIDF + hh];
    __syncthreads();
    if (hh < CLSF) {
        float s = lin_b[hh];
#pragma unroll 16
        for (int d = 0; d < HIDF; d++) s += gl[d] * lin_w[d * CLSF + hh];
        out[g * CLSF + hh] = s;
    }
}

extern "C" void kernel_launch(void* const* d_in, const int* in_sizes, int n_in,
                              void* d_out, int out_size, void* d_ws, size_t ws_size,
                              hipStream_t stream) {
    const float* x     = (const float*)d_in[0];
    const int*   ei    = (const int*)d_in[1];
    const int*   et    = (const int*)d_in[2];
    const int*   batch = (const int*)d_in[3];
    const float* W1    = (const float*)d_in[4];
    const float* root1 = (const float*)d_in[5];
    const float* b1    = (const float*)d_in[6];
    const float* W2    = (const float*)d_in[7];
    const float* root2 = (const float*)d_in[8];
    const float* b2    = (const float*)d_in[9];
    const float* lin_w = (const float*)d_in[10];
    const float* lin_b = (const float*)d_in[11];
    float* out = (float*)d_out;

    const int* src = ei;            // edge_index[0]
    const int* dst = ei + N_EDGES;  // edge_index[1]

    char* ws = (char*)d_ws;
    unsigned short* ab  = (unsigned short*)ws; ws += (size_t)N_NODES * KTOT * 2;  // 115.2 MB
    unsigned short* wt1 = (unsigned short*)ws; ws += (size_t)HIDF * KTOT * 2;     // 288 KB
    unsigned short* wt2 = (unsigned short*)ws; ws += (size_t)HIDF * KTOT * 2;
    unsigned short* h2b = (unsigned short*)ws; ws += (size_t)N_NODES * HIDF * 2;  // 12.8 MB
    int*   cnt    = (int*)ws;   ws += (size_t)S_SEG * 4;
    int*   off    = (int*)ws;   ws += (size_t)S_SEG * 4;
    int*   bsum   = (int*)ws;   ws += 512 * 4;
    int*   cursor = (int*)ws;   ws += (size_t)S_SEG * 4;
    int*   sorted_src = (int*)ws; ws += (size_t)N_EDGES * 4;
    float* gmean  = (float*)ws; ws += (size_t)G_GRAPHS * HIDF * 4;

    hipMemsetAsync(cnt, 0, (size_t)S_SEG * 4, stream);
    hipMemsetAsync(cursor, 0, (size_t)S_SEG * 4, stream);

    // ---- counting sort of edges by (dst, rel) segment ----
    count_kernel<<<(N_EDGES + 255) / 256, 256, 0, stream>>>(dst, et, cnt);
    scan1_kernel<<<NB_SCAN, SCAN_BLK, 0, stream>>>(cnt, off, bsum);
    scan2_kernel<<<1, 512, 0, stream>>>(bsum);
    bin_kernel<<<(N_EDGES + 255) / 256, 256, 0, stream>>>(src, dst, et, off, bsum,
                                                          cursor, sorted_src);

    // ---- bf16 conversions: x -> ab tail; weights -> transposed bf16 ----
    convx_kernel<<<(N_NODES * D_INF + 255) / 256, 256, 0, stream>>>(x, ab);
    convw_kernel<<<dim3(KTOT / 16, HIDF / 16), 256, 0, stream>>>(W1, root1, wt1);
    convw_kernel<<<dim3(KTOT / 16, HIDF / 16), 256, 0, stream>>>(W2, root2, wt2);

    // ---- layer 1 (gemm writes relu(h1) bf16 in-place into ab tail) ----
    agg_kernel<<<(S_SEG + 7) / 8, 256, 0, stream>>>(ab, sorted_src, off, bsum, cnt, ab);
    gemm_mfma<<<(N_NODES + 127) / 128, 256, 0, stream>>>(ab, wt1, b1, ab + KREL, KTOT);

    // ---- layer 2 ----
    agg_kernel<<<(S_SEG + 7) / 8, 256, 0, stream>>>(ab, sorted_src, off, bsum, cnt, ab);
    gemm_mfma<<<(N_NODES + 127) / 128, 256, 0, stream>>>(ab, wt2, b2, h2b, HIDF);

    // ---- pool + classify ----
    pool_kernel<<<G_GRAPHS, 256, 0, stream>>>(h2b, batch, gmean);
    final_kernel<<<G_GRAPHS, HIDF, 0, stream>>>(gmean, lin_w, lin_b, out);

    (void)in_sizes; (void)n_in; (void)out_size; (void)ws_size;
}